// Round 1
// baseline (1271.307 us; speedup 1.0000x reference)
//
#include <hip/hip_runtime.h>

// Flash attention fwd, fp32, B=2 S=8192 D=64, scale = 1/8.
// Round 1: correctness-first fp32 baseline (no fp32 MFMA exists on CDNA4;
// vector-FMA roofline ~220us). Register-tiled 4x4, float4 LDS reads,
// online softmax fully in registers (row owned by one 16-lane group).

#define SEQ 8192
#define DH 64
#define BQ 64
#define BK 64
#define LDSS 68  // LDS row stride in floats: 16B-aligned, row delta -> bank+4

__global__ __launch_bounds__(256, 1) void attn_fwd_f32(
    const float* __restrict__ Q, const float* __restrict__ K,
    const float* __restrict__ V, float* __restrict__ O)
{
    __shared__ float Qs[BQ * LDSS];
    __shared__ float Ks[BK * LDSS];
    __shared__ float Vt[DH * LDSS];  // transposed: Vt[d][k]
    __shared__ float Ps[BQ * LDSS];

    const int tid = threadIdx.x;
    const int tx = tid & 15;        // col group (also lane%16 within wave)
    const int ty = tid >> 4;        // row group
    const int batch = blockIdx.y;
    const int q0 = blockIdx.x * BQ;

    const float* Qb = Q + ((size_t)batch * SEQ + q0) * DH;
    const float* Kb = K + (size_t)batch * SEQ * DH;
    const float* Vb = V + (size_t)batch * SEQ * DH;

    // ---- load Q tile (64x64 floats = 1024 float4, 4 per thread) ----
#pragma unroll
    for (int i = 0; i < 4; ++i) {
        int f = tid + 256 * i;       // float4 index
        int r = f >> 4;              // row (16 float4 per row)
        int c4 = f & 15;
        float4 qv = ((const float4*)Qb)[f];
        *(float4*)&Qs[r * LDSS + c4 * 4] = qv;
    }

    float acc[4][4] = {};
    float mrow[4], lrow[4];
#pragma unroll
    for (int i = 0; i < 4; ++i) { mrow[i] = -1e30f; lrow[i] = 0.0f; }

    for (int kt = 0; kt < SEQ; kt += BK) {
        const float* Kt = Kb + (size_t)kt * DH;
        const float* Vg = Vb + (size_t)kt * DH;

        __syncthreads();  // previous PV phase done before overwriting Ks/Vt
#pragma unroll
        for (int i = 0; i < 4; ++i) {
            int f = tid + 256 * i;
            int r = f >> 4;
            int c4 = f & 15;
            float4 kv = ((const float4*)Kt)[f];
            *(float4*)&Ks[r * LDSS + c4 * 4] = kv;
            float4 vv = ((const float4*)Vg)[f];
            // transpose into Vt[d][k]: global (k=r, d=4*c4+m)
            Vt[(c4 * 4 + 0) * LDSS + r] = vv.x;
            Vt[(c4 * 4 + 1) * LDSS + r] = vv.y;
            Vt[(c4 * 4 + 2) * LDSS + r] = vv.z;
            Vt[(c4 * 4 + 3) * LDSS + r] = vv.w;
        }
        __syncthreads();

        // ---- S = Q K^T  (4x4 tile per thread, rows ty+16i, cols tx+16j) ----
        float s[4][4] = {};
#pragma unroll
        for (int k4 = 0; k4 < DH; k4 += 4) {
            float4 qv[4], kv[4];
#pragma unroll
            for (int i = 0; i < 4; ++i)
                qv[i] = *(const float4*)&Qs[(ty + 16 * i) * LDSS + k4];
#pragma unroll
            for (int j = 0; j < 4; ++j)
                kv[j] = *(const float4*)&Ks[(tx + 16 * j) * LDSS + k4];
#pragma unroll
            for (int i = 0; i < 4; ++i)
#pragma unroll
                for (int j = 0; j < 4; ++j)
                    s[i][j] += qv[i].x * kv[j].x + qv[i].y * kv[j].y +
                               qv[i].z * kv[j].z + qv[i].w * kv[j].w;
        }

        // ---- online softmax (rows owned by aligned 16-lane groups) ----
        float p[4][4];
#pragma unroll
        for (int i = 0; i < 4; ++i) {
#pragma unroll
            for (int j = 0; j < 4; ++j) s[i][j] *= 0.125f;
            float tm = fmaxf(fmaxf(s[i][0], s[i][1]), fmaxf(s[i][2], s[i][3]));
#pragma unroll
            for (int off = 1; off < 16; off <<= 1)
                tm = fmaxf(tm, __shfl_xor(tm, off, 64));
            float mnew = fmaxf(mrow[i], tm);
            float sc = __expf(mrow[i] - mnew);
            float lsum = 0.0f;
#pragma unroll
            for (int j = 0; j < 4; ++j) {
                float pe = __expf(s[i][j] - mnew);
                p[i][j] = pe;
                lsum += pe;
            }
#pragma unroll
            for (int off = 1; off < 16; off <<= 1)
                lsum += __shfl_xor(lsum, off, 64);
            lrow[i] = lrow[i] * sc + lsum;
            mrow[i] = mnew;
#pragma unroll
            for (int j = 0; j < 4; ++j) acc[i][j] *= sc;
#pragma unroll
            for (int j = 0; j < 4; ++j)
                Ps[(ty + 16 * i) * LDSS + tx + 16 * j] = p[i][j];
        }
        __syncthreads();

        // ---- O += P V  (rows ty+16i, d-cols tx+16j) ----
#pragma unroll
        for (int k4 = 0; k4 < BK; k4 += 4) {
            float4 pr[4], vr[4];
#pragma unroll
            for (int i = 0; i < 4; ++i)
                pr[i] = *(const float4*)&Ps[(ty + 16 * i) * LDSS + k4];
#pragma unroll
            for (int j = 0; j < 4; ++j)
                vr[j] = *(const float4*)&Vt[(tx + 16 * j) * LDSS + k4];
#pragma unroll
            for (int i = 0; i < 4; ++i)
#pragma unroll
                for (int j = 0; j < 4; ++j)
                    acc[i][j] += pr[i].x * vr[j].x + pr[i].y * vr[j].y +
                                 pr[i].z * vr[j].z + pr[i].w * vr[j].w;
        }
    }

    // ---- epilogue: normalize and store ----
    float* Ob = O + ((size_t)batch * SEQ + q0) * DH;
#pragma unroll
    for (int i = 0; i < 4; ++i) {
        float inv = 1.0f / lrow[i];
#pragma unroll
        for (int j = 0; j < 4; ++j)
            Ob[(ty + 16 * i) * DH + tx + 16 * j] = acc[i][j] * inv;
    }
}

extern "C" void kernel_launch(void* const* d_in, const int* in_sizes, int n_in,
                              void* d_out, int out_size, void* d_ws, size_t ws_size,
                              hipStream_t stream) {
    (void)n_in; (void)d_ws; (void)ws_size; (void)out_size;
    const float* x1 = (const float*)d_in[0];
    const float* x2 = (const float*)d_in[1];
    const float* x3 = (const float*)d_in[2];
    float* out = (float*)d_out;
    const int B = in_sizes[0] / (SEQ * DH);  // = 2
    dim3 grid(SEQ / BQ, B);
    attn_fwd_f32<<<grid, 256, 0, stream>>>(x1, x2, x3, out);
}

// Round 3
// 233.647 us; speedup vs baseline: 5.4412x; 5.4412x over previous
//
#include <hip/hip_runtime.h>

// Flash attention fwd via bf16 MFMA. B=2 S=8192 D=64, scale 1/8 folded into Q.
// 256 blocks x 512 threads: BQ=64 rows/block, 2 wave-groups split the key space
// (split-K flash, merged at end), 4 waves/group each owning 16 q-rows.
// mfma_f32_16x16x32_bf16; A-frag: A[l&15][(l>>4)*8+e]; C/D: row=(l>>4)*4+reg,
// col=l&15 (m89-verified). All LDS tiles XOR-swizzled (byte ^= (row&7)<<4).

#define SEQ 8192
#define DH  64
#define BQ  64
#define BK  64
#define NT  (SEQ / 2 / BK)   // 64 K-tiles per wave-group

typedef __attribute__((ext_vector_type(8))) short  short8v;
typedef __attribute__((ext_vector_type(4))) float  f32x4;

#define OFF_K 0            // [grp] 8192 B each  (bf16 64x64 row-major, swizzled)
#define OFF_V 16384        // [grp] 8192 B each  (bf16 Vt[d][k], swizzled)
#define OFF_P 32768        // [wid] 2048 B each  (bf16 16x64, swizzled)
#define LDS_BYTES 49152
// merge aliases (after main loop): A0 f32[64][68] at 0; M0/L0 at 20480/20736

__device__ __forceinline__ ushort f2bf(float f) {
    uint u = __float_as_uint(f);
    return (ushort)((u + 0x7FFFu + ((u >> 16) & 1u)) >> 16);  // RNE
}
__device__ __forceinline__ uint swz(uint row, uint colByte) {
    return row * 128u + (colByte ^ ((row & 7u) << 4));
}

__global__ __launch_bounds__(512, 2) void attn_fwd_mfma(
    const float* __restrict__ Q, const float* __restrict__ K,
    const float* __restrict__ V, float* __restrict__ O)
{
    __shared__ ulong2 smem_[LDS_BYTES / 16];
    char* smem = (char*)smem_;

    const int tid  = threadIdx.x;
    const int lane = tid & 63;
    const int wid  = tid >> 6;      // 0..7
    const int grp  = wid >> 2;      // key-space half
    const int w    = wid & 3;       // wave within group
    const int l15  = lane & 15;
    const int l4   = lane >> 4;     // 0..3
    const int batch = blockIdx.y;
    const int q0    = blockIdx.x * BQ;
    const int m0    = w * 16;       // q-rows [m0, m0+16) of this block

    const float* Qb = Q + ((size_t)batch * SEQ + q0) * DH;
    const float* Kb = K + ((size_t)batch * SEQ + (size_t)grp * (SEQ / 2)) * DH;
    const float* Vb = V + ((size_t)batch * SEQ + (size_t)grp * (SEQ / 2)) * DH;

    // ---- Q fragments (registers, scale 1/8 folded in; exact pow2) ----
    short8v qf[2];
    {
        const float* qr = Qb + (m0 + l15) * DH;
#pragma unroll
        for (int t = 0; t < 2; ++t) {
            float4 a = *(const float4*)(qr + t * 32 + l4 * 8);
            float4 b = *(const float4*)(qr + t * 32 + l4 * 8 + 4);
            short8v v;
            v[0] = (short)f2bf(a.x * 0.125f); v[1] = (short)f2bf(a.y * 0.125f);
            v[2] = (short)f2bf(a.z * 0.125f); v[3] = (short)f2bf(a.w * 0.125f);
            v[4] = (short)f2bf(b.x * 0.125f); v[5] = (short)f2bf(b.y * 0.125f);
            v[6] = (short)f2bf(b.z * 0.125f); v[7] = (short)f2bf(b.w * 0.125f);
            qf[t] = v;
        }
    }

    const int tg  = tid & 255;      // thread id within wave-group
    const int k2  = tg & 31;        // V: key-pair index
    const int dq0 = tg >> 5;        // V: d-quad index (0..7)

    char* kb = smem + OFF_K + grp * 8192;
    char* vb = smem + OFF_V + grp * 8192;
    char* pb = smem + OFF_P + wid * 2048;

    float4 kp[4], vp[4];  // prefetch registers

    auto issue = [&](int kt) {
        const float* Kt = Kb + (size_t)kt * BK * DH;
        const float* Vt = Vb + (size_t)kt * BK * DH;
#pragma unroll
        for (int i = 0; i < 4; ++i) kp[i] = ((const float4*)Kt)[tg + 256 * i];
#pragma unroll
        for (int dd = 0; dd < 2; ++dd) {
            int dq = dq0 + 8 * dd;
            vp[2 * dd]     = *(const float4*)(Vt + (2 * k2) * DH + 4 * dq);
            vp[2 * dd + 1] = *(const float4*)(Vt + (2 * k2 + 1) * DH + 4 * dq);
        }
    };
    auto stash = [&]() {
#pragma unroll
        for (int i = 0; i < 4; ++i) {
            int f = tg + 256 * i;
            uint row = (uint)(f >> 4), c4 = (uint)(f & 15);
            uint2 h;
            h.x = (uint)f2bf(kp[i].x) | ((uint)f2bf(kp[i].y) << 16);
            h.y = (uint)f2bf(kp[i].z) | ((uint)f2bf(kp[i].w) << 16);
            *(uint2*)(kb + swz(row, c4 * 8)) = h;
        }
#pragma unroll
        for (int dd = 0; dd < 2; ++dd) {
            int dq = dq0 + 8 * dd;
            float a0[4] = {vp[2*dd].x, vp[2*dd].y, vp[2*dd].z, vp[2*dd].w};
            float a1[4] = {vp[2*dd+1].x, vp[2*dd+1].y, vp[2*dd+1].z, vp[2*dd+1].w};
#pragma unroll
            for (int e = 0; e < 4; ++e) {
                uint pk = (uint)f2bf(a0[e]) | ((uint)f2bf(a1[e]) << 16);
                *(uint*)(vb + swz((uint)(4 * dq + e), (uint)(4 * k2))) = pk;
            }
        }
    };

    f32x4 o[4];
#pragma unroll
    for (int j = 0; j < 4; ++j) o[j] = (f32x4){0.f, 0.f, 0.f, 0.f};
    float mrow[4] = {-1e30f, -1e30f, -1e30f, -1e30f};
    float lrow[4] = {0.f, 0.f, 0.f, 0.f};

    issue(0);
    stash();
    __syncthreads();

    for (int kt = 0; kt < NT; ++kt) {
        if (kt + 1 < NT) issue(kt + 1);

        // ---- S = Q' K^T ----
        f32x4 s[4];
#pragma unroll
        for (int j = 0; j < 4; ++j) s[j] = (f32x4){0.f, 0.f, 0.f, 0.f};
#pragma unroll
        for (int t = 0; t < 2; ++t) {
#pragma unroll
            for (int j = 0; j < 4; ++j) {
                short8v kf = *(const short8v*)(kb + swz((uint)(j * 16 + l15),
                                                        (uint)(t * 64 + l4 * 16)));
                s[j] = __builtin_amdgcn_mfma_f32_16x16x32_bf16(qf[t], kf, s[j], 0, 0, 0);
            }
        }

        // ---- online softmax (row r lives in the lane's 16-lane group) ----
#pragma unroll
        for (int r = 0; r < 4; ++r) {
            float tm = fmaxf(fmaxf(s[0][r], s[1][r]), fmaxf(s[2][r], s[3][r]));
            tm = fmaxf(tm, __shfl_xor(tm, 1));
            tm = fmaxf(tm, __shfl_xor(tm, 2));
            tm = fmaxf(tm, __shfl_xor(tm, 4));
            tm = fmaxf(tm, __shfl_xor(tm, 8));
            float mn = fmaxf(mrow[r], tm);
            float sc = __expf(mrow[r] - mn);
            mrow[r] = mn;
            float p0 = __expf(s[0][r] - mn);
            float p1 = __expf(s[1][r] - mn);
            float p2 = __expf(s[2][r] - mn);
            float p3 = __expf(s[3][r] - mn);
            float ls = (p0 + p1) + (p2 + p3);
            ls += __shfl_xor(ls, 1);
            ls += __shfl_xor(ls, 2);
            ls += __shfl_xor(ls, 4);
            ls += __shfl_xor(ls, 8);
            lrow[r] = lrow[r] * sc + ls;
            o[0][r] *= sc; o[1][r] *= sc; o[2][r] *= sc; o[3][r] *= sc;
            uint rowb = (uint)(l4 * 4 + r);
            *(ushort*)(pb + swz(rowb, (uint)((0 * 16 + l15) * 2))) = f2bf(p0);
            *(ushort*)(pb + swz(rowb, (uint)((1 * 16 + l15) * 2))) = f2bf(p1);
            *(ushort*)(pb + swz(rowb, (uint)((2 * 16 + l15) * 2))) = f2bf(p2);
            *(ushort*)(pb + swz(rowb, (uint)((3 * 16 + l15) * 2))) = f2bf(p3);
        }

        // ---- O += P V ----
        short8v pf[2];
#pragma unroll
        for (int t = 0; t < 2; ++t)
            pf[t] = *(const short8v*)(pb + swz((uint)l15, (uint)(t * 64 + l4 * 16)));
#pragma unroll
        for (int t = 0; t < 2; ++t) {
#pragma unroll
            for (int j = 0; j < 4; ++j) {
                short8v vf = *(const short8v*)(vb + swz((uint)(j * 16 + l15),
                                                        (uint)(t * 64 + l4 * 16)));
                o[j] = __builtin_amdgcn_mfma_f32_16x16x32_bf16(pf[t], vf, o[j], 0, 0, 0);
            }
        }

        __syncthreads();
        if (kt + 1 < NT) stash();
        __syncthreads();
    }

    // ---- split-K merge across the two wave-groups ----
    float* A0 = (float*)smem;                    // [64][68] f32
    float* M0 = (float*)(smem + 20480);          // [64]
    float* L0 = (float*)(smem + 20736);          // [64]

    if (grp == 0) {
#pragma unroll
        for (int r = 0; r < 4; ++r) {
            uint rowA = (uint)(m0 + l4 * 4 + r);
#pragma unroll
            for (int j = 0; j < 4; ++j)
                A0[rowA * 68 + j * 16 + l15] = o[j][r];
            if (l15 == 0) { M0[rowA] = mrow[r]; L0[rowA] = lrow[r]; }
        }
    }
    __syncthreads();
    if (grp == 1) {
        float* Ob = O + ((size_t)batch * SEQ + q0) * DH;
#pragma unroll
        for (int r = 0; r < 4; ++r) {
            uint rowA = (uint)(m0 + l4 * 4 + r);
            float m1 = mrow[r], l1 = lrow[r];
            float m0r = M0[rowA], l0r = L0[rowA];
            float mn = fmaxf(m0r, m1);
            float s0 = __expf(m0r - mn), s1 = __expf(m1 - mn);
            float inv = 1.0f / (l0r * s0 + l1 * s1);
#pragma unroll
            for (int j = 0; j < 4; ++j) {
                float af = A0[rowA * 68 + j * 16 + l15] * s0 + o[j][r] * s1;
                Ob[rowA * DH + j * 16 + l15] = af * inv;
            }
        }
    }
}

extern "C" void kernel_launch(void* const* d_in, const int* in_sizes, int n_in,
                              void* d_out, int out_size, void* d_ws, size_t ws_size,
                              hipStream_t stream) {
    (void)n_in; (void)d_ws; (void)ws_size; (void)out_size;
    const float* x1 = (const float*)d_in[0];
    const float* x2 = (const float*)d_in[1];
    const float* x3 = (const float*)d_in[2];
    float* out = (float*)d_out;
    const int B = in_sizes[0] / (SEQ * DH);  // = 2
    dim3 grid(SEQ / BQ, B);
    attn_fwd_mfma<<<grid, 512, 0, stream>>>(x1, x2, x3, out);
}

// Round 4
// 182.182 us; speedup vs baseline: 6.9782x; 1.2825x over previous
//
#include <hip/hip_runtime.h>

// Flash attention fwd, B=2 S=8192 D=64. Round 4: register-resident design.
// Pre-pass: Q*0.125 -> bf16 [b][s][d]; K -> bf16 [b][s][d]; V -> bf16 Vt[b][d][s].
// Main: 512 blocks x 4 waves; wave = 32 q-rows x 2048-key quarter (split-K 4).
// Swapped 32x32x16 MFMAs: S^T = mfma(K,Q), O^T = mfma(Vt,P). Softmax in-register
// (lane owns one q-row: col=lane&31). No LDS/barriers in main loop; LDS merge at end.
// C/D layout (m74/m101): col=lane&31, row=(reg&3)+8*(reg>>2)+4*(lane>>5).
// A/B frag: [row=lane&31][k=(lane>>5)*8+e].

#define SEQ 8192
#define DH  64
#define KQ  2048         // keys per quarter
#define NTK (KQ / 64)    // 32 tiles

typedef __attribute__((ext_vector_type(8)))  short short8v;
typedef __attribute__((ext_vector_type(16))) float f32x16;

__device__ __forceinline__ uint f2bf(float f) {
    uint u = __float_as_uint(f);
    return (u + 0x7FFFu + ((u >> 16) & 1u)) >> 16;  // RNE
}

// ---------------- pre-pass: Q/K convert ----------------
__global__ void conv_qk(const float* __restrict__ Q, const float* __restrict__ K,
                        ushort* __restrict__ Qb, ushort* __restrict__ Kb, int n4) {
    int idx = blockIdx.x * 256 + threadIdx.x;
    if (idx >= n4) return;
    float4 qv = ((const float4*)Q)[idx];
    float4 kv = ((const float4*)K)[idx];
    uint2 qo, ko;
    qo.x = f2bf(qv.x * 0.125f) | (f2bf(qv.y * 0.125f) << 16);
    qo.y = f2bf(qv.z * 0.125f) | (f2bf(qv.w * 0.125f) << 16);
    ko.x = f2bf(kv.x) | (f2bf(kv.y) << 16);
    ko.y = f2bf(kv.z) | (f2bf(kv.w) << 16);
    ((uint2*)Qb)[idx] = qo;
    ((uint2*)Kb)[idx] = ko;
}

// ---------------- pre-pass: V transpose ----------------
__global__ void conv_vt(const float* __restrict__ V, ushort* __restrict__ Vt) {
    __shared__ ushort T[64][65];
    const int tid = threadIdx.x;
    const int s0 = blockIdx.x * 64, b = blockIdx.y;
    const float* base = V + ((size_t)b * SEQ + s0) * DH;
#pragma unroll
    for (int i = 0; i < 4; ++i) {
        int f4 = tid + 256 * i;
        int sl = f4 >> 4, d4 = (f4 & 15) * 4;
        float4 v = *(const float4*)(base + sl * DH + d4);
        T[d4 + 0][sl] = (ushort)f2bf(v.x);
        T[d4 + 1][sl] = (ushort)f2bf(v.y);
        T[d4 + 2][sl] = (ushort)f2bf(v.z);
        T[d4 + 3][sl] = (ushort)f2bf(v.w);
    }
    __syncthreads();
    ushort* outb = Vt + (size_t)b * DH * SEQ + s0;
#pragma unroll
    for (int i = 0; i < 8; ++i) {
        int u = tid + 256 * i;
        int d = u >> 5, s2 = (u & 31) * 2;
        uint pk = (uint)T[d][s2] | ((uint)T[d][s2 + 1] << 16);
        *(uint*)(outb + (size_t)d * SEQ + s2) = pk;
    }
}

// ---------------- main kernel ----------------
__global__ __launch_bounds__(256, 2) void attn_fwd_reg(
    const ushort* __restrict__ Qb, const ushort* __restrict__ Kb,
    const ushort* __restrict__ Vt, float* __restrict__ O)
{
    __shared__ float Sp[4][64][33];
    __shared__ float Ml[4][2][32];

    const int tid = threadIdx.x;
    const int lane = tid & 63;
    const int wid = tid >> 6;       // key quarter
    const int q = lane & 31;        // this lane's q-row (within tile)
    const int hi = lane >> 5;
    const int b = blockIdx.y;
    const int q0 = blockIdx.x * 32;

    // Q B-frags (scale already folded in pre-pass)
    const ushort* Qr = Qb + ((size_t)b * SEQ + q0 + q) * DH + 8 * hi;
    short8v qf[4];
#pragma unroll
    for (int t = 0; t < 4; ++t) qf[t] = *(const short8v*)(Qr + 16 * t);

    const ushort* Kl = Kb + ((size_t)b * SEQ + wid * KQ + q) * DH + 8 * hi;
    const ushort* Vl = Vt + ((size_t)b * DH + q) * SEQ + wid * KQ + 8 * hi;

    f32x16 o0, o1;
#pragma unroll
    for (int j = 0; j < 16; ++j) { o0[j] = 0.f; o1[j] = 0.f; }
    float m = -1e30f, l = 0.f;

    // K frags for tile 0
    short8v ka[8];
#pragma unroll
    for (int kb = 0; kb < 2; ++kb)
#pragma unroll
        for (int t = 0; t < 4; ++t)
            ka[kb * 4 + t] = *(const short8v*)(Kl + (size_t)(kb * 32) * DH + 16 * t);

    for (int kt = 0; kt < NTK; ++kt) {
        // V frags for this tile (land during softmax)
        const ushort* Vp = Vl + kt * 64;
        short8v va[8];
#pragma unroll
        for (int db = 0; db < 2; ++db)
#pragma unroll
            for (int kc = 0; kc < 4; ++kc)
                va[db * 4 + kc] = *(const short8v*)(Vp + (size_t)(db * 32) * SEQ + 16 * kc);

        // S^T = K Q^T  (rows=keys, cols=q)
        f32x16 s0, s1;
#pragma unroll
        for (int j = 0; j < 16; ++j) { s0[j] = 0.f; s1[j] = 0.f; }
#pragma unroll
        for (int t = 0; t < 4; ++t) {
            s0 = __builtin_amdgcn_mfma_f32_32x32x16_bf16(ka[t],     qf[t], s0, 0, 0, 0);
            s1 = __builtin_amdgcn_mfma_f32_32x32x16_bf16(ka[4 + t], qf[t], s1, 0, 0, 0);
        }

        // prefetch next tile's K (ka dead after QK^T)
        if (kt + 1 < NTK) {
            const ushort* Kn = Kl + (size_t)(kt + 1) * 64 * DH;
#pragma unroll
            for (int kb = 0; kb < 2; ++kb)
#pragma unroll
                for (int t = 0; t < 4; ++t)
                    ka[kb * 4 + t] = *(const short8v*)(Kn + (size_t)(kb * 32) * DH + 16 * t);
        }

        // ---- in-register online softmax (lane owns q-row; keys split by hi-parity) ----
        float tm;
        {
            f32x16 tv;
#pragma unroll
            for (int j = 0; j < 16; ++j) tv[j] = fmaxf(s0[j], s1[j]);
#pragma unroll
            for (int j = 0; j < 8; ++j) tv[j] = fmaxf(tv[j], tv[j + 8]);
#pragma unroll
            for (int j = 0; j < 4; ++j) tv[j] = fmaxf(tv[j], tv[j + 4]);
            tm = fmaxf(fmaxf(tv[0], tv[1]), fmaxf(tv[2], tv[3]));
        }
        tm = fmaxf(tm, __shfl_xor(tm, 32));
        float mnew = fmaxf(m, tm);
        if (__any(mnew > m)) {
            float sc = __expf(m - mnew);
            l *= sc;
#pragma unroll
            for (int j = 0; j < 16; ++j) { o0[j] *= sc; o1[j] *= sc; }
            m = mnew;
        }
#pragma unroll
        for (int j = 0; j < 16; ++j) {
            s0[j] = __expf(s0[j] - m);
            s1[j] = __expf(s1[j] - m);
        }
        {
            f32x16 pa;
#pragma unroll
            for (int j = 0; j < 16; ++j) pa[j] = s0[j] + s1[j];
#pragma unroll
            for (int j = 0; j < 8; ++j) pa[j] += pa[j + 8];
#pragma unroll
            for (int j = 0; j < 4; ++j) pa[j] += pa[j + 4];
            float ls = (pa[0] + pa[1]) + (pa[2] + pa[3]);
            ls += __shfl_xor(ls, 32);
            l += ls;
        }

        // ---- pack P to bf16 words W[16]; W[2i+c] = pk(p[4G+2c], p[4G+2c+1]), G=2i+hi ----
        uint W[16];
#pragma unroll
        for (int i = 0; i < 8; ++i) {
#pragma unroll
            for (int c = 0; c < 2; ++c) {
                int kb = i >> 2, rg = ((i & 3) << 2) | (c << 1);
                float lo = kb ? s1[rg] : s0[rg];
                float hh = kb ? s1[rg + 1] : s0[rg + 1];
                uint w;
                asm("v_cvt_pk_bf16_f32 %0, %1, %2" : "=v"(w) : "v"(lo), "v"(hh));
                W[2 * i + c] = w;
            }
        }
        // ---- cross-half exchange -> B-frags (keys 16kc+8hi+e at lane (q,hi)) ----
        short8v bfrag[4];
#pragma unroll
        for (int kc = 0; kc < 4; ++kc) {
            uint w0 = W[4 * kc], w1 = W[4 * kc + 1], w2 = W[4 * kc + 2], w3 = W[4 * kc + 3];
            uint y02 = hi ? w0 : w2;
            uint z02 = __shfl_xor(y02, 32);
            uint y13 = hi ? w1 : w3;
            uint z13 = __shfl_xor(y13, 32);
            union { uint u[4]; short8v v; } cv;
            cv.u[0] = hi ? z02 : w0;
            cv.u[1] = hi ? z13 : w1;
            cv.u[2] = hi ? w2 : z02;
            cv.u[3] = hi ? w3 : z13;
            bfrag[kc] = cv.v;
        }

        // ---- O^T += V^T P^T ----
#pragma unroll
        for (int kc = 0; kc < 4; ++kc) {
            o0 = __builtin_amdgcn_mfma_f32_32x32x16_bf16(va[kc],     bfrag[kc], o0, 0, 0, 0);
            o1 = __builtin_amdgcn_mfma_f32_32x32x16_bf16(va[4 + kc], bfrag[kc], o1, 0, 0, 0);
        }
    }

    // ---- write partials, merge 4 quarters ----
#pragma unroll
    for (int rg = 0; rg < 16; ++rg) {
        int d = (rg & 3) + 8 * (rg >> 2) + 4 * hi;
        Sp[wid][d][q]      = o0[rg];
        Sp[wid][d + 32][q] = o1[rg];
    }
    if (hi == 0) { Ml[wid][0][q] = m; Ml[wid][1][q] = l; }
    __syncthreads();

    float* Ob = O + ((size_t)b * SEQ + q0) * DH;
#pragma unroll
    for (int it = 0; it < 2; ++it) {
        int f4 = tid + 256 * it;
        int qq = f4 >> 4, d4 = (f4 & 15) * 4;
        float m0 = Ml[0][0][qq], m1 = Ml[1][0][qq], m2 = Ml[2][0][qq], m3 = Ml[3][0][qq];
        float ms = fmaxf(fmaxf(m0, m1), fmaxf(m2, m3));
        float e0 = __expf(m0 - ms), e1 = __expf(m1 - ms),
              e2 = __expf(m2 - ms), e3 = __expf(m3 - ms);
        float lt = Ml[0][1][qq] * e0 + Ml[1][1][qq] * e1 +
                   Ml[2][1][qq] * e2 + Ml[3][1][qq] * e3;
        float inv = 1.0f / lt;
        float4 r;
        r.x = (Sp[0][d4+0][qq]*e0 + Sp[1][d4+0][qq]*e1 + Sp[2][d4+0][qq]*e2 + Sp[3][d4+0][qq]*e3) * inv;
        r.y = (Sp[0][d4+1][qq]*e0 + Sp[1][d4+1][qq]*e1 + Sp[2][d4+1][qq]*e2 + Sp[3][d4+1][qq]*e3) * inv;
        r.z = (Sp[0][d4+2][qq]*e0 + Sp[1][d4+2][qq]*e1 + Sp[2][d4+2][qq]*e2 + Sp[3][d4+2][qq]*e3) * inv;
        r.w = (Sp[0][d4+3][qq]*e0 + Sp[1][d4+3][qq]*e1 + Sp[2][d4+3][qq]*e2 + Sp[3][d4+3][qq]*e3) * inv;
        *(float4*)(Ob + (size_t)qq * DH + d4) = r;
    }
}

// ================= fallback (round-3 kernel) if ws too small =================
#define BQ  64
#define BK  64
#define NT  (SEQ / 2 / BK)
typedef __attribute__((ext_vector_type(4))) float f32x4;
#define OFF_K 0
#define OFF_V 16384
#define OFF_P 32768
#define LDS_BYTES 49152

__device__ __forceinline__ ushort f2bfs(float f) {
    uint u = __float_as_uint(f);
    return (ushort)((u + 0x7FFFu + ((u >> 16) & 1u)) >> 16);
}
__device__ __forceinline__ uint swz(uint row, uint colByte) {
    return row * 128u + (colByte ^ ((row & 7u) << 4));
}

__global__ __launch_bounds__(512, 2) void attn_fwd_mfma(
    const float* __restrict__ Q, const float* __restrict__ K,
    const float* __restrict__ V, float* __restrict__ O)
{
    __shared__ ulong2 smem_[LDS_BYTES / 16];
    char* smem = (char*)smem_;
    const int tid = threadIdx.x;
    const int lane = tid & 63;
    const int wid = tid >> 6;
    const int grp = wid >> 2;
    const int w = wid & 3;
    const int l15 = lane & 15;
    const int l4 = lane >> 4;
    const int batch = blockIdx.y;
    const int q0 = blockIdx.x * BQ;
    const int m0 = w * 16;
    const float* Qb = Q + ((size_t)batch * SEQ + q0) * DH;
    const float* Kb = K + ((size_t)batch * SEQ + (size_t)grp * (SEQ / 2)) * DH;
    const float* Vb = V + ((size_t)batch * SEQ + (size_t)grp * (SEQ / 2)) * DH;
    short8v qf[2];
    {
        const float* qr = Qb + (m0 + l15) * DH;
#pragma unroll
        for (int t = 0; t < 2; ++t) {
            float4 a = *(const float4*)(qr + t * 32 + l4 * 8);
            float4 bb = *(const float4*)(qr + t * 32 + l4 * 8 + 4);
            short8v v;
            v[0] = (short)f2bfs(a.x * 0.125f); v[1] = (short)f2bfs(a.y * 0.125f);
            v[2] = (short)f2bfs(a.z * 0.125f); v[3] = (short)f2bfs(a.w * 0.125f);
            v[4] = (short)f2bfs(bb.x * 0.125f); v[5] = (short)f2bfs(bb.y * 0.125f);
            v[6] = (short)f2bfs(bb.z * 0.125f); v[7] = (short)f2bfs(bb.w * 0.125f);
            qf[t] = v;
        }
    }
    const int tg = tid & 255;
    const int k2 = tg & 31;
    const int dq0 = tg >> 5;
    char* kb = smem + OFF_K + grp * 8192;
    char* vb = smem + OFF_V + grp * 8192;
    char* pb = smem + OFF_P + wid * 2048;
    float4 kp[4], vp[4];
    auto issue = [&](int kt) {
        const float* Kt = Kb + (size_t)kt * BK * DH;
        const float* Vtp = Vb + (size_t)kt * BK * DH;
#pragma unroll
        for (int i = 0; i < 4; ++i) kp[i] = ((const float4*)Kt)[tg + 256 * i];
#pragma unroll
        for (int dd = 0; dd < 2; ++dd) {
            int dq = dq0 + 8 * dd;
            vp[2 * dd] = *(const float4*)(Vtp + (2 * k2) * DH + 4 * dq);
            vp[2 * dd + 1] = *(const float4*)(Vtp + (2 * k2 + 1) * DH + 4 * dq);
        }
    };
    auto stash = [&]() {
#pragma unroll
        for (int i = 0; i < 4; ++i) {
            int f = tg + 256 * i;
            uint row = (uint)(f >> 4), c4 = (uint)(f & 15);
            uint2 h;
            h.x = (uint)f2bfs(kp[i].x) | ((uint)f2bfs(kp[i].y) << 16);
            h.y = (uint)f2bfs(kp[i].z) | ((uint)f2bfs(kp[i].w) << 16);
            *(uint2*)(kb + swz(row, c4 * 8)) = h;
        }
#pragma unroll
        for (int dd = 0; dd < 2; ++dd) {
            int dq = dq0 + 8 * dd;
            float a0[4] = {vp[2*dd].x, vp[2*dd].y, vp[2*dd].z, vp[2*dd].w};
            float a1[4] = {vp[2*dd+1].x, vp[2*dd+1].y, vp[2*dd+1].z, vp[2*dd+1].w};
#pragma unroll
            for (int e = 0; e < 4; ++e) {
                uint pk = (uint)f2bfs(a0[e]) | ((uint)f2bfs(a1[e]) << 16);
                *(uint*)(vb + swz((uint)(4 * dq + e), (uint)(4 * k2))) = pk;
            }
        }
    };
    f32x4 o[4];
#pragma unroll
    for (int j = 0; j < 4; ++j) o[j] = (f32x4){0.f, 0.f, 0.f, 0.f};
    float mrow[4] = {-1e30f, -1e30f, -1e30f, -1e30f};
    float lrow[4] = {0.f, 0.f, 0.f, 0.f};
    issue(0);
    stash();
    __syncthreads();
    for (int kt = 0; kt < NT; ++kt) {
        if (kt + 1 < NT) issue(kt + 1);
        f32x4 s[4];
#pragma unroll
        for (int j = 0; j < 4; ++j) s[j] = (f32x4){0.f, 0.f, 0.f, 0.f};
#pragma unroll
        for (int t = 0; t < 2; ++t) {
#pragma unroll
            for (int j = 0; j < 4; ++j) {
                short8v kf = *(const short8v*)(kb + swz((uint)(j * 16 + l15),
                                                        (uint)(t * 64 + l4 * 16)));
                s[j] = __builtin_amdgcn_mfma_f32_16x16x32_bf16(qf[t], kf, s[j], 0, 0, 0);
            }
        }
#pragma unroll
        for (int r = 0; r < 4; ++r) {
            float tm = fmaxf(fmaxf(s[0][r], s[1][r]), fmaxf(s[2][r], s[3][r]));
            tm = fmaxf(tm, __shfl_xor(tm, 1));
            tm = fmaxf(tm, __shfl_xor(tm, 2));
            tm = fmaxf(tm, __shfl_xor(tm, 4));
            tm = fmaxf(tm, __shfl_xor(tm, 8));
            float mn = fmaxf(mrow[r], tm);
            float sc = __expf(mrow[r] - mn);
            mrow[r] = mn;
            float p0 = __expf(s[0][r] - mn);
            float p1 = __expf(s[1][r] - mn);
            float p2 = __expf(s[2][r] - mn);
            float p3 = __expf(s[3][r] - mn);
            float ls = (p0 + p1) + (p2 + p3);
            ls += __shfl_xor(ls, 1);
            ls += __shfl_xor(ls, 2);
            ls += __shfl_xor(ls, 4);
            ls += __shfl_xor(ls, 8);
            lrow[r] = lrow[r] * sc + ls;
            o[0][r] *= sc; o[1][r] *= sc; o[2][r] *= sc; o[3][r] *= sc;
            uint rowb = (uint)(l4 * 4 + r);
            *(ushort*)(pb + swz(rowb, (uint)((0 * 16 + l15) * 2))) = f2bfs(p0);
            *(ushort*)(pb + swz(rowb, (uint)((1 * 16 + l15) * 2))) = f2bfs(p1);
            *(ushort*)(pb + swz(rowb, (uint)((2 * 16 + l15) * 2))) = f2bfs(p2);
            *(ushort*)(pb + swz(rowb, (uint)((3 * 16 + l15) * 2))) = f2bfs(p3);
        }
        short8v pf[2];
#pragma unroll
        for (int t = 0; t < 2; ++t)
            pf[t] = *(const short8v*)(pb + swz((uint)l15, (uint)(t * 64 + l4 * 16)));
#pragma unroll
        for (int t = 0; t < 2; ++t) {
#pragma unroll
            for (int j = 0; j < 4; ++j) {
                short8v vf = *(const short8v*)(vb + swz((uint)(j * 16 + l15),
                                                        (uint)(t * 64 + l4 * 16)));
                o[j] = __builtin_amdgcn_mfma_f32_16x16x32_bf16(pf[t], vf, o[j], 0, 0, 0);
            }
        }
        __syncthreads();
        if (kt + 1 < NT) stash();
        __syncthreads();
    }
    float* A0 = (float*)smem;
    float* M0 = (float*)(smem + 20480);
    float* L0 = (float*)(smem + 20736);
    if (grp == 0) {
#pragma unroll
        for (int r = 0; r < 4; ++r) {
            uint rowA = (uint)(m0 + l4 * 4 + r);
#pragma unroll
            for (int j = 0; j < 4; ++j)
                A0[rowA * 68 + j * 16 + l15] = o[j][r];
            if (l15 == 0) { M0[rowA] = mrow[r]; L0[rowA] = lrow[r]; }
        }
    }
    __syncthreads();
    if (grp == 1) {
        float* Ob = O + ((size_t)batch * SEQ + q0) * DH;
#pragma unroll
        for (int r = 0; r < 4; ++r) {
            uint rowA = (uint)(m0 + l4 * 4 + r);
            float m1 = mrow[r], l1 = lrow[r];
            float m0r = M0[rowA], l0r = L0[rowA];
            float mn = fmaxf(m0r, m1);
            float s0 = __expf(m0r - mn), s1 = __expf(m1 - mn);
            float inv = 1.0f / (l0r * s0 + l1 * s1);
#pragma unroll
            for (int j = 0; j < 4; ++j) {
                float af = A0[rowA * 68 + j * 16 + l15] * s0 + o[j][r] * s1;
                Ob[rowA * DH + j * 16 + l15] = af * inv;
            }
        }
    }
}

extern "C" void kernel_launch(void* const* d_in, const int* in_sizes, int n_in,
                              void* d_out, int out_size, void* d_ws, size_t ws_size,
                              hipStream_t stream) {
    (void)n_in; (void)out_size;
    const float* x1 = (const float*)d_in[0];
    const float* x2 = (const float*)d_in[1];
    const float* x3 = (const float*)d_in[2];
    float* out = (float*)d_out;
    const int B = in_sizes[0] / (SEQ * DH);
    const size_t tsz = (size_t)B * SEQ * DH * sizeof(ushort);

    if (ws_size >= 3 * tsz) {
        ushort* Qb = (ushort*)d_ws;
        ushort* Kb = (ushort*)((char*)d_ws + tsz);
        ushort* Vtp = (ushort*)((char*)d_ws + 2 * tsz);
        int n4 = B * SEQ * DH / 4;
        conv_qk<<<(n4 + 255) / 256, 256, 0, stream>>>(x1, x2, Qb, Kb, n4);
        conv_vt<<<dim3(SEQ / 64, B), 256, 0, stream>>>(x3, Vtp);
        attn_fwd_reg<<<dim3(SEQ / 32, B), 256, 0, stream>>>(Qb, Kb, Vtp, out);
    } else {
        attn_fwd_mfma<<<dim3(SEQ / BQ, B), 512, 0, stream>>>(x1, x2, x3, out);
    }
}